// Round 10
// baseline (363.193 us; speedup 1.0000x reference)
//
#include <hip/hip_runtime.h>

#define F_IN 256
#define CHUNK 8192
#define ESL_CAP 10240

typedef short bf8_t __attribute__((ext_vector_type(8)));   // 8 bf16
typedef float f4_t  __attribute__((ext_vector_type(4)));   // 4 fp32 acc

__device__ __forceinline__ unsigned short f2bf(float f) {
  unsigned u = __float_as_uint(f);
  unsigned r = (u + 0x7FFFu + ((u >> 16) & 1u)) >> 16;  // RNE
  return (unsigned short)r;
}
#define BF_LO(d) __uint_as_float((d) << 16)
#define BF_HI(d) __uint_as_float((d) & 0xFFFF0000u)

__device__ __forceinline__ bf8_t pack8(float4 a, float4 b) {
  bf8_t r;
  r[0] = (short)f2bf(a.x); r[1] = (short)f2bf(a.y);
  r[2] = (short)f2bf(a.z); r[3] = (short)f2bf(a.w);
  r[4] = (short)f2bf(b.x); r[5] = (short)f2bf(b.y);
  r[6] = (short)f2bf(b.z); r[7] = (short)f2bf(b.w);
  return r;
}

// ------- W prep: WbT[n][k] = bf16(W[k][n])  (one-time, 32 KB) ----------------
__global__ __launch_bounds__(256) void wprep_kernel(
    const float* __restrict__ W, unsigned short* __restrict__ WbT) {
  const int i = blockIdx.x * 256 + threadIdx.x;  // 0..16383
  const int k = i >> 6, n = i & 63;
  WbT[n * 256 + k] = f2bf(W[i]);
}

// ------- direct GEMM: hb = bf16(dinv[row]*(x @ W)); A from global, B in LDS --
__global__ __launch_bounds__(256) void gemm_direct_kernel(
    const float* __restrict__ x, const unsigned short* __restrict__ WbT,
    const float* __restrict__ dinvp, unsigned short* __restrict__ hb, int M) {
  __shared__ short Bs[64][264];   // [n][k], stride 264 -> 2-way banks (free)
  const int t = threadIdx.x;
  for (int i = t; i < 2048; i += 256) {
    const int n = i >> 5, kq = (i & 31) << 3;
    *(uint4*)&Bs[n][kq] = *(const uint4*)(WbT + n * 256 + kq);
  }
  __syncthreads();

  const int brow = blockIdx.x * 128;
  const int w = t >> 6;
  const int l = t & 63;
  const int ml = l & 15;
  const int quad = l >> 4;

  const int r0 = min(brow + w * 32 + ml, M - 1);
  const int r1 = min(brow + w * 32 + 16 + ml, M - 1);
  const float* xr0 = x + (size_t)r0 * F_IN + (quad << 3);
  const float* xr1 = x + (size_t)r1 * F_IN + (quad << 3);

  f4_t acc[2][4];
#pragma unroll
  for (int a = 0; a < 2; ++a)
#pragma unroll
    for (int b = 0; b < 4; ++b) acc[a][b] = (f4_t){0.f, 0.f, 0.f, 0.f};

#pragma unroll
  for (int k0 = 0; k0 < F_IN; k0 += 32) {
    bf8_t afr[2];
    {
      const float4 a0 = *(const float4*)(xr0 + k0);
      const float4 a1 = *(const float4*)(xr0 + k0 + 4);
      afr[0] = pack8(a0, a1);
      const float4 c0 = *(const float4*)(xr1 + k0);
      const float4 c1 = *(const float4*)(xr1 + k0 + 4);
      afr[1] = pack8(c0, c1);
    }
    bf8_t bfr[4];
#pragma unroll
    for (int nt = 0; nt < 4; ++nt)
      bfr[nt] = *(const bf8_t*)&Bs[nt * 16 + ml][k0 + (quad << 3)];
#pragma unroll
    for (int mt = 0; mt < 2; ++mt)
#pragma unroll
      for (int nt = 0; nt < 4; ++nt)
        acc[mt][nt] = __builtin_amdgcn_mfma_f32_16x16x32_bf16(
            afr[mt], bfr[nt], acc[mt][nt], 0, 0, 0);
  }

#pragma unroll
  for (int mt = 0; mt < 2; ++mt) {
#pragma unroll
    for (int reg = 0; reg < 4; ++reg) {
      const int row = brow + w * 32 + mt * 16 + (quad << 2) + reg;
      if (row < M) {
        const float di = dinvp[row];
#pragma unroll
        for (int nt = 0; nt < 4; ++nt)
          hb[(size_t)row * 64 + nt * 16 + ml] = f2bf(di * acc[mt][nt][reg]);
      }
    }
  }
}

// ------- block-local sort: each chunk sorted by bucket into own region -------
__global__ __launch_bounds__(512) void sort_local_kernel(
    const int* __restrict__ src_arr, const int* __restrict__ dst_arr,
    int* __restrict__ espB, int* __restrict__ segStart, int* __restrict__ segCnt,
    int E, int NBK) {
  __shared__ int hist[512];
  __shared__ int s[512];
  __shared__ int cur[512];
  const int t = threadIdx.x;
  const int blk = blockIdx.x;
  const int base = blk * CHUNK;
  const int cnt = min(CHUNK, E - base);
  for (int i = t; i < NBK; i += 512) hist[i] = 0;
  __syncthreads();
  int pk[16], bk[16];
#pragma unroll
  for (int k = 0; k < 16; ++k) {
    const int i = t + k * 512;
    bk[k] = -1;
    if (i < cnt) {
      const int sv = src_arr[base + i];
      const int dv = dst_arr[base + i];
      pk[k] = sv | ((dv & 255) << 24);
      bk[k] = dv >> 8;
      atomicAdd(&hist[bk[k]], 1);
    }
  }
  __syncthreads();
  const int v = (t < NBK) ? hist[t] : 0;
  s[t] = v;
  __syncthreads();
#pragma unroll
  for (int off = 1; off < 512; off <<= 1) {
    int add = (t >= off) ? s[t - off] : 0;
    __syncthreads();
    s[t] += add;
    __syncthreads();
  }
  if (t < NBK) {
    const int excl = s[t] - v;
    cur[t] = excl;
    segStart[blk * NBK + t] = base + excl;   // block-major: dense writes
    segCnt[blk * NBK + t] = v;
  }
  __syncthreads();
#pragma unroll
  for (int k = 0; k < 16; ++k) {
    if (bk[k] >= 0) {
      const int pos = atomicAdd(&cur[bk[k]], 1);
      espB[base + pos] = pk[k];              // dense 32 KB streaming write
    }
  }
}

// ------- per-bucket degree -> dinvp (needed before gemm) ---------------------
__global__ __launch_bounds__(512) void deg_seg_kernel(
    const int* __restrict__ espB, const int* __restrict__ segStart,
    const int* __restrict__ segCnt, float* __restrict__ dinvp,
    int N, int NBK, int NCH) {
  __shared__ int segS[512];
  __shared__ int segC[512];
  __shared__ int hist[256];
  const int t = threadIdx.x;
  const int b = blockIdx.x;
  if (t < 256) hist[t] = 0;
  if (t < 512) { segS[t] = 0; segC[t] = 0; }
  __syncthreads();
  for (int i = t; i < NCH; i += 512) {
    segS[i] = segStart[i * NBK + b];
    segC[i] = segCnt[i * NBK + b];
  }
  __syncthreads();
  const int wid = t >> 6, lane = t & 63;
  for (int seg = wid; seg < NCH; seg += 8) {
    const int sS = segS[seg], c = segC[seg];
    for (int j = lane; j < c; j += 64)
      atomicAdd(&hist[((unsigned)espB[sS + j]) >> 24], 1);
  }
  __syncthreads();
  const int node = b * 256 + t;
  if (t < 256 && node < N) dinvp[node] = rsqrtf((float)(hist[t] + 1));
}

// ------- FUSED per-bucket: bin->LDS CSR, agg gather, MFMA MLP, write out -----
__global__ __launch_bounds__(1024) void fused_agg_mlp_kernel(
    const unsigned short* __restrict__ hb, const int* __restrict__ espB,
    const int* __restrict__ segStart, const int* __restrict__ segCnt,
    const float* __restrict__ bg,
    const float* __restrict__ W1, const float* __restrict__ b1,
    const float* __restrict__ W2, const float* __restrict__ b2,
    const float* __restrict__ W3, const float* __restrict__ b3,
    float* __restrict__ out, int N, int NBK, int NCH) {
  __shared__ int esL[ESL_CAP];      // bucket edge list (srcs), 40 KB
  __shared__ short g64[256 * 72];   // g bf16 (h1 aliases after barrier)
  __shared__ short h2s[256 * 40];   // layer-2 out, cols 16..31 zero
  __shared__ short W1s[32 * 72];
  __shared__ short W2s[16 * 40];
  __shared__ short W3s[16 * 40];
  __shared__ int segS[512], segC[512];
  __shared__ int deg[256], rp[257], cur[256], sbuf[256];
  __shared__ float bgs[64], b1s[32], b2s[16], b3s[16];
  short* h1s = g64;

  const int t = threadIdx.x;
  const int b = blockIdx.x;
  const int node0 = b * 256;

  for (int i = t; i < 256 * 40; i += 1024) h2s[i] = 0;
  for (int i = t; i < 16 * 40; i += 1024) W3s[i] = 0;
  if (t < 256) deg[t] = 0;
  if (t < 512) { segS[t] = 0; segC[t] = 0; }
  if (t < 64) bgs[t] = bg[t];
  if (t < 32) b1s[t] = b1[t];
  if (t < 16) { b2s[t] = b2[t]; b3s[t] = (t < 10) ? b3[t] : 0.f; }
  for (int i = t; i < NCH; i += 1024) {
    segS[i] = segStart[i * NBK + b];
    segC[i] = segCnt[i * NBK + b];
  }
  for (int i = t; i < 2048; i += 1024) { const int k = i >> 5, n = i & 31; W1s[n * 72 + k] = (short)f2bf(W1[i]); }
  for (int i = t; i < 512;  i += 1024) { const int k = i >> 4, n = i & 15; W2s[n * 40 + k] = (short)f2bf(W2[i]); }
  if (t < 160) { const int k = t / 10, n = t % 10; W3s[n * 40 + k] = (short)f2bf(W3[t]); }
  __syncthreads();

  const int wid = t >> 6, lane = t & 63;

  // pass 1: per-node histogram
  for (int seg = wid; seg < NCH; seg += 16) {
    const int sS = segS[seg], c = segC[seg];
    for (int j = lane; j < c; j += 64)
      atomicAdd(&deg[((unsigned)espB[sS + j]) >> 24], 1);
  }
  __syncthreads();

  // scan 256 bins
  int v = 0;
  if (t < 256) { v = deg[t]; sbuf[t] = v; }
  __syncthreads();
#pragma unroll
  for (int off = 1; off < 256; off <<= 1) {
    int add = 0;
    if (t < 256 && t >= off) add = sbuf[t - off];
    __syncthreads();
    if (t < 256) sbuf[t] += add;
    __syncthreads();
  }
  if (t < 256) { rp[t] = sbuf[t] - v; cur[t] = sbuf[t] - v; }
  if (t == 255) rp[256] = sbuf[255];
  __syncthreads();

  // pass 2: scatter srcs into LDS CSR
  for (int seg = wid; seg < NCH; seg += 16) {
    const int sS = segS[seg], c = segC[seg];
    for (int j = lane; j < c; j += 64) {
      const int p = espB[sS + j];
      const int pos = atomicAdd(&cur[((unsigned)p) >> 24], 1);
      esL[pos] = p & 0x00FFFFFF;
    }
  }
  __syncthreads();

  // aggregation: 16 waves, each handles nodes wid, wid+16, ...
  const int slot = lane >> 3;
  const int fq = (lane & 7) << 3;
  for (int node = wid; node < 256; node += 16) {
    const int start = rp[node];
    const int end = rp[node + 1];
    float acc[8] = {0.f};
    int i = start + slot;
    for (; i + 8 < end; i += 16) {
      const int s0 = esL[i];
      const int s1 = esL[i + 8];
      const uint4 r0 = *(const uint4*)(hb + (size_t)s0 * 64 + fq);
      const uint4 r1 = *(const uint4*)(hb + (size_t)s1 * 64 + fq);
      acc[0] += BF_LO(r0.x) + BF_LO(r1.x);
      acc[1] += BF_HI(r0.x) + BF_HI(r1.x);
      acc[2] += BF_LO(r0.y) + BF_LO(r1.y);
      acc[3] += BF_HI(r0.y) + BF_HI(r1.y);
      acc[4] += BF_LO(r0.z) + BF_LO(r1.z);
      acc[5] += BF_HI(r0.z) + BF_HI(r1.z);
      acc[6] += BF_LO(r0.w) + BF_LO(r1.w);
      acc[7] += BF_HI(r0.w) + BF_HI(r1.w);
    }
    if (i < end) {
      const int s0 = esL[i];
      const uint4 r0 = *(const uint4*)(hb + (size_t)s0 * 64 + fq);
      acc[0] += BF_LO(r0.x);
      acc[1] += BF_HI(r0.x);
      acc[2] += BF_LO(r0.y);
      acc[3] += BF_HI(r0.y);
      acc[4] += BF_LO(r0.z);
      acc[5] += BF_HI(r0.z);
      acc[6] += BF_LO(r0.w);
      acc[7] += BF_HI(r0.w);
    }
#pragma unroll
    for (int m = 8; m <= 32; m <<= 1)
#pragma unroll
      for (int j = 0; j < 8; ++j) acc[j] += __shfl_xor(acc[j], m, 64);

    if (slot == 0) {
      const int gn = node0 + node;
      if (gn < N) {  // self-loop: += hb[node] (pre-scaled by own dinv)
        const uint4 r = *(const uint4*)(hb + (size_t)gn * 64 + fq);
        acc[0] += BF_LO(r.x); acc[1] += BF_HI(r.x);
        acc[2] += BF_LO(r.y); acc[3] += BF_HI(r.y);
        acc[4] += BF_LO(r.z); acc[5] += BF_HI(r.z);
        acc[6] += BF_LO(r.w); acc[7] += BF_HI(r.w);
      }
      const float di = rsqrtf((float)(deg[node] + 1));
      bf8_t g;
#pragma unroll
      for (int j = 0; j < 8; ++j)
        g[j] = (short)f2bf(fmaxf(di * acc[j] + bgs[fq + j], 0.f));
      *(bf8_t*)&g64[node * 72 + fq] = g;
    }
  }
  __syncthreads();

  // MFMA MLP: wave wid handles rows rb..rb+15
  const int rb = wid * 16;
  const int ml = lane & 15;
  const int quad = lane >> 4;

  // layer 1: (256x64)@(64x32)
  bf8_t a1f[2], b1f[2][2];
#pragma unroll
  for (int ks = 0; ks < 2; ++ks)
    a1f[ks] = *(const bf8_t*)&g64[(rb + ml) * 72 + ks * 32 + quad * 8];
#pragma unroll
  for (int nt = 0; nt < 2; ++nt)
#pragma unroll
    for (int ks = 0; ks < 2; ++ks)
      b1f[nt][ks] = *(const bf8_t*)&W1s[(nt * 16 + ml) * 72 + ks * 32 + quad * 8];
  f4_t acc1[2];
#pragma unroll
  for (int nt = 0; nt < 2; ++nt) acc1[nt] = (f4_t){0.f, 0.f, 0.f, 0.f};
#pragma unroll
  for (int ks = 0; ks < 2; ++ks)
#pragma unroll
    for (int nt = 0; nt < 2; ++nt)
      acc1[nt] = __builtin_amdgcn_mfma_f32_16x16x32_bf16(
          a1f[ks], b1f[nt][ks], acc1[nt], 0, 0, 0);
  __syncthreads();  // all g64 reads done before h1 alias writes
#pragma unroll
  for (int nt = 0; nt < 2; ++nt)
#pragma unroll
    for (int reg = 0; reg < 4; ++reg) {
      const int row = rb + quad * 4 + reg;
      const int col = nt * 16 + ml;
      h1s[row * 40 + col] = (short)f2bf(fmaxf(acc1[nt][reg] + b1s[col], 0.f));
    }
  __syncthreads();

  // layer 2: (256x32)@(32x16)
  const bf8_t a2f = *(const bf8_t*)&h1s[(rb + ml) * 40 + quad * 8];
  const bf8_t b2f = *(const bf8_t*)&W2s[ml * 40 + quad * 8];
  f4_t acc2 = (f4_t){0.f, 0.f, 0.f, 0.f};
  acc2 = __builtin_amdgcn_mfma_f32_16x16x32_bf16(a2f, b2f, acc2, 0, 0, 0);
  __syncthreads();
#pragma unroll
  for (int reg = 0; reg < 4; ++reg) {
    const int row = rb + quad * 4 + reg;
    h2s[row * 40 + ml] = (short)f2bf(fmaxf(acc2[reg] + b2s[ml], 0.f));
  }
  __syncthreads();

  // layer 3: (256x16)@(16x10), K zero-padded
  const bf8_t a3f = *(const bf8_t*)&h2s[(rb + ml) * 40 + quad * 8];
  const bf8_t b3f = *(const bf8_t*)&W3s[ml * 40 + quad * 8];
  f4_t acc3 = (f4_t){0.f, 0.f, 0.f, 0.f};
  acc3 = __builtin_amdgcn_mfma_f32_16x16x32_bf16(a3f, b3f, acc3, 0, 0, 0);
#pragma unroll
  for (int reg = 0; reg < 4; ++reg) {
    const int node = node0 + rb + quad * 4 + reg;
    if (ml < 10 && node < N) out[(size_t)node * 10 + ml] = acc3[reg] + b3s[ml];
  }
}

extern "C" void kernel_launch(void* const* d_in, const int* in_sizes, int n_in,
                              void* d_out, int out_size, void* d_ws, size_t ws_size,
                              hipStream_t stream) {
  const float* x     = (const float*)d_in[0];
  const int*   ei    = (const int*)d_in[1];
  const float* W_gcn = (const float*)d_in[2];
  const float* b_gcn = (const float*)d_in[3];
  const float* W1    = (const float*)d_in[4];
  const float* b1    = (const float*)d_in[5];
  const float* W2    = (const float*)d_in[6];
  const float* b2    = (const float*)d_in[7];
  const float* W3    = (const float*)d_in[8];
  const float* b3    = (const float*)d_in[9];
  float* out = (float*)d_out;

  const int N = in_sizes[0] / F_IN;   // 100000
  const int E = in_sizes[1] / 2;      // 3200000
  const int* src = ei;
  const int* dst = ei + E;
  const int NBK = (N + 255) >> 8;           // 391 buckets of 256 nodes
  const int NCH = (E + CHUNK - 1) / CHUNK;  // 391 chunks

  unsigned short* hb = (unsigned short*)d_ws;            // N*64 us  (12.8 MB)
  float* dinvp       = (float*)(hb + (size_t)N * 64);    // N f
  int*   espB        = (int*)(dinvp + N);                // E i      (12.8 MB)
  int*   segStart    = espB + E;                         // NCH*NBK i (0.61 MB)
  int*   segCnt      = segStart + NCH * NBK;             // NCH*NBK i (0.61 MB)
  unsigned short* WbT= (unsigned short*)(segCnt + NCH * NBK); // 16384 us

  wprep_kernel<<<64, 256, 0, stream>>>(W_gcn, WbT);
  sort_local_kernel<<<NCH, 512, 0, stream>>>(src, dst, espB, segStart, segCnt, E, NBK);
  deg_seg_kernel<<<NBK, 512, 0, stream>>>(espB, segStart, segCnt, dinvp, N, NBK, NCH);
  gemm_direct_kernel<<<(N + 127) / 128, 256, 0, stream>>>(x, WbT, dinvp, hb, N);
  fused_agg_mlp_kernel<<<NBK, 1024, 0, stream>>>(
      hb, espB, segStart, segCnt, b_gcn, W1, b1, W2, b2, W3, b3, out, N, NBK, NCH);
}